// Round 1
// baseline (3197.171 us; speedup 1.0000x reference)
//
#include <hip/hip_runtime.h>
#include <hip/hip_bf16.h>
#include <math.h>

#define NTOT   32768
#define NPER   4096
#define NGRAPH 8
#define EDGES  262144
#define HCH    128
#define EPSBN  1e-5f

__device__ __forceinline__ float eluf(float x){ return x > 0.f ? x : expm1f(x); }

// ---------------- CSR build (per launch, deterministic up to fp atomic order) ----------------
__global__ __launch_bounds__(256) void k_hist(const int* __restrict__ dst, int* __restrict__ deg){
    int e = blockIdx.x * 256 + threadIdx.x;
    atomicAdd(&deg[dst[e]], 1);
}

__global__ __launch_bounds__(1024) void k_scan(const int* __restrict__ deg, int* __restrict__ rowptr,
                                               int* __restrict__ cursor){
    __shared__ int part[1024];
    int t = threadIdx.x;
    const int chunk = NTOT / 1024;            // 32
    int base = t * chunk;
    int s = 0;
    for (int j = 0; j < chunk; ++j) s += deg[base + j];
    part[t] = s; __syncthreads();
    for (int off = 1; off < 1024; off <<= 1){
        int v = (t >= off) ? part[t - off] : 0;
        __syncthreads();
        part[t] += v;
        __syncthreads();
    }
    int run = part[t] - s;                    // exclusive prefix
    for (int j = 0; j < chunk; ++j){
        rowptr[base + j] = run; cursor[base + j] = run;
        run += deg[base + j];
    }
    if (t == 1023) rowptr[NTOT] = run;
}

__global__ __launch_bounds__(256) void k_scatter(const int* __restrict__ src, const int* __restrict__ dst,
                                                 const float* __restrict__ L, int* __restrict__ cursor,
                                                 int* __restrict__ esrc, float* __restrict__ ew){
    int e = blockIdx.x * 256 + threadIdx.x;
    int d = dst[e];
    int pos = atomicAdd(&cursor[d], 1);
    esrc[pos] = src[e];
    ew[pos]   = L[e];
}

// ---------------- conv1: H = x@W1+b1 ; U = elu(H) ; stats -> sums[0] ----------------
__global__ __launch_bounds__(256) void k_conv1(const float* __restrict__ x, const float* __restrict__ W1,
                                               const float* __restrict__ b1, float* __restrict__ H,
                                               float* __restrict__ U, float* __restrict__ sums0){
    __shared__ float red[2][2][128];
    int t = threadIdx.x, ch = t & 127, pr = t >> 7;
    float w0 = W1[ch], w1 = W1[128 + ch], w2 = W1[256 + ch], bv = b1[ch];
    int base = blockIdx.x * 128;
    float ls = 0.f, lss = 0.f;
    for (int it = 0; it < 64; ++it){
        int row = base + 2 * it + pr;
        const float* xr = x + (size_t)row * 3;
        float h = fmaf(xr[2], w2, fmaf(xr[1], w1, fmaf(xr[0], w0, bv)));
        H[(size_t)row * HCH + ch] = h;
        float u = eluf(h);
        U[(size_t)row * HCH + ch] = u;
        ls += u; lss += u * u;
    }
    red[0][pr][ch] = ls; red[1][pr][ch] = lss;
    __syncthreads();
    if (t < 128){
        atomicAdd(&sums0[t],       red[0][0][t] + red[0][1][t]);
        atomicAdd(&sums0[256 + t], red[1][0][t] + red[1][1][t]);
    }
}

// ---------------- SpMM (CSR by dst) + BN stats for agg half ----------------
__global__ __launch_bounds__(256) void k_spmm(const float* __restrict__ U, const int* __restrict__ rowptr,
                                              const int* __restrict__ esrc, const float* __restrict__ ew,
                                              float* __restrict__ AGG, float* __restrict__ sums_k){
    __shared__ float red[2][2][128];
    int t = threadIdx.x, ch = t & 127, pr = t >> 7;
    int nb = blockIdx.x * 32;
    float ls = 0.f, lss = 0.f;
    for (int s2 = 0; s2 < 16; ++s2){
        int node = nb + 2 * s2 + pr;
        int e0 = rowptr[node], e1 = rowptr[node + 1];
        float acc = 0.f;
        for (int e = e0; e < e1; ++e)
            acc = fmaf(U[(size_t)esrc[e] * HCH + ch], ew[e], acc);
        AGG[(size_t)node * HCH + ch] = acc;
        ls += acc; lss += acc * acc;
    }
    red[0][pr][ch] = ls; red[1][pr][ch] = lss;
    __syncthreads();
    if (t < 128){
        atomicAdd(&sums_k[128 + t], red[0][0][t] + red[0][1][t]);
        atomicAdd(&sums_k[384 + t], red[1][0][t] + red[1][1][t]);
    }
}

// ---------------- masked per-graph sums for gavg layers ----------------
__global__ __launch_bounds__(256) void k_gavg(const float* __restrict__ U, const float* __restrict__ mask,
                                              float* __restrict__ gsum_k, float* __restrict__ gcnt_k){
    __shared__ float red[2][128];
    __shared__ float redc[2];
    int t = threadIdx.x, ch = t & 127, pr = t >> 7;
    int g = blockIdx.y;
    int base = g * NPER + blockIdx.x * 128;
    float ls = 0.f, lc = 0.f;
    for (int it = 0; it < 64; ++it){
        int row = base + 2 * it + pr;
        float mk = mask[row];
        ls = fmaf(U[(size_t)row * HCH + ch], mk, ls);
        if (ch == 0) lc += mk;
    }
    red[pr][ch] = ls;
    if (ch == 0) redc[pr] = lc;
    __syncthreads();
    if (t < 128) atomicAdd(&gsum_k[g * HCH + t], red[0][t] + red[1][t]);
    if (t == 0)  atomicAdd(&gcnt_k[g], redc[0] + redc[1]);
}

// ---------------- fused BN+GEMM (+bias, +residual) + ELU + next-layer stats ----------------
// MODE 0: agg half from AGG buffer (spmm layers). MODE 1: agg half = per-graph broadcast mean.
// RES 1: add residual from Hres and write Hout (second inner conv). RES 0: Hout not written.
template<int MODE, int RES>
__global__ __launch_bounds__(256) void k_gemm(
        const float* __restrict__ U, const float* __restrict__ AGG,
        const float* __restrict__ gsum_k, const float* __restrict__ gcnt_k,
        const float* __restrict__ sums_k,
        const float* __restrict__ gamma, const float* __restrict__ beta,
        const float* __restrict__ W, const float* __restrict__ bias,
        const float* __restrict__ Hres, float* __restrict__ Hout,
        float* __restrict__ Uout, float* __restrict__ sums_n)
{
    __shared__ float s_s[256], s_shift[256], s_avgn[128];
    __shared__ float zs[64][68];     // 272B row stride, 16B aligned
    __shared__ float wsm[64][132];   // 528B row stride, 16B aligned
    __shared__ float red[2][8][128];
    const int t = threadIdx.x;
    const int row0 = blockIdx.x * 64;

    if (t < 256){
        float m, ex2;
        if (MODE == 1 && t >= 128){
            float S1 = 0.f, S2 = 0.f;
            #pragma unroll
            for (int g = 0; g < NGRAPH; ++g){
                float a = gsum_k[g * HCH + (t - 128)] / gcnt_k[g];
                S1 += a; S2 += a * a;
            }
            m = S1 * (1.f / NGRAPH); ex2 = S2 * (1.f / NGRAPH);
        } else {
            m   = sums_k[t]       * (1.f / NTOT);
            ex2 = sums_k[256 + t] * (1.f / NTOT);
        }
        float var = ex2 - m * m;
        float sc = gamma[t] * rsqrtf(var + EPSBN);
        s_s[t] = sc;
        s_shift[t] = beta[t] - m * sc;
    }
    __syncthreads();
    if (MODE == 1 && t < 128){
        int g0 = row0 >> 12;
        float a = gsum_k[g0 * HCH + t] / gcnt_k[g0];
        s_avgn[t] = a * s_s[128 + t] + s_shift[128 + t];
        // first read of s_avgn happens after >=2 __syncthreads (chunk 2 load) -> ordered
    }

    float acc[8][4];
    #pragma unroll
    for (int ri = 0; ri < 8; ++ri)
        #pragma unroll
        for (int j = 0; j < 4; ++j) acc[ri][j] = 0.f;
    const int tc = t & 31, tr = t >> 5;

    for (int chnk = 0; chnk < 4; ++chnk){
        const int cb = chnk * 64;
        // stage z tile (affine-normalized on load)
        #pragma unroll
        for (int i = 0; i < 4; ++i){
            int f = t + 256 * i;
            int r = f >> 4;
            int c4 = (f & 15) << 2;
            float4 v;
            if (chnk < 2){
                const float4 g4 = *(const float4*)(U + (size_t)(row0 + r) * HCH + cb + c4);
                int c = cb + c4;
                v.x = g4.x * s_s[c + 0] + s_shift[c + 0];
                v.y = g4.y * s_s[c + 1] + s_shift[c + 1];
                v.z = g4.z * s_s[c + 2] + s_shift[c + 2];
                v.w = g4.w * s_s[c + 3] + s_shift[c + 3];
            } else if (MODE == 0){
                const float4 g4 = *(const float4*)(AGG + (size_t)(row0 + r) * HCH + (cb - 128) + c4);
                int c = cb + c4;
                v.x = g4.x * s_s[c + 0] + s_shift[c + 0];
                v.y = g4.y * s_s[c + 1] + s_shift[c + 1];
                v.z = g4.z * s_s[c + 2] + s_shift[c + 2];
                v.w = g4.w * s_s[c + 3] + s_shift[c + 3];
            } else {
                int c = cb - 128 + c4;
                v.x = s_avgn[c + 0]; v.y = s_avgn[c + 1];
                v.z = s_avgn[c + 2]; v.w = s_avgn[c + 3];
            }
            *(float4*)&zs[r][c4] = v;
        }
        // stage W tile
        #pragma unroll
        for (int i = 0; i < 8; ++i){
            int f = t + 256 * i;
            int kr = f >> 5;
            int c4 = (f & 31) << 2;
            *(float4*)&wsm[kr][c4] = *(const float4*)(W + (size_t)(cb + kr) * HCH + c4);
        }
        __syncthreads();
        #pragma unroll
        for (int k = 0; k < 64; k += 4){
            float4 wv[4];
            #pragma unroll
            for (int kk = 0; kk < 4; ++kk) wv[kk] = *(const float4*)&wsm[k + kk][tc * 4];
            #pragma unroll
            for (int ri = 0; ri < 8; ++ri){
                float4 zr = *(const float4*)&zs[tr + 8 * ri][k];
                float zf[4] = {zr.x, zr.y, zr.z, zr.w};
                #pragma unroll
                for (int kk = 0; kk < 4; ++kk){
                    acc[ri][0] = fmaf(zf[kk], wv[kk].x, acc[ri][0]);
                    acc[ri][1] = fmaf(zf[kk], wv[kk].y, acc[ri][1]);
                    acc[ri][2] = fmaf(zf[kk], wv[kk].z, acc[ri][2]);
                    acc[ri][3] = fmaf(zf[kk], wv[kk].w, acc[ri][3]);
                }
            }
        }
        __syncthreads();
    }

    // epilogue: bias (+res) -> h ; u = elu(h) ; stats for next layer
    float b0 = bias[tc * 4 + 0], b1v = bias[tc * 4 + 1];
    float b2v = bias[tc * 4 + 2], b3 = bias[tc * 4 + 3];
    float ls0=0,ls1=0,ls2=0,ls3=0, lq0=0,lq1=0,lq2=0,lq3=0;
    #pragma unroll
    for (int ri = 0; ri < 8; ++ri){
        int row = row0 + tr + 8 * ri;
        float4 h;
        h.x = acc[ri][0] + b0; h.y = acc[ri][1] + b1v;
        h.z = acc[ri][2] + b2v; h.w = acc[ri][3] + b3;
        if (RES){
            float4 rv = *(const float4*)(Hres + (size_t)row * HCH + tc * 4);
            h.x += rv.x; h.y += rv.y; h.z += rv.z; h.w += rv.w;
            *(float4*)(Hout + (size_t)row * HCH + tc * 4) = h;
        }
        float4 u;
        u.x = eluf(h.x); u.y = eluf(h.y); u.z = eluf(h.z); u.w = eluf(h.w);
        *(float4*)(Uout + (size_t)row * HCH + tc * 4) = u;
        ls0 += u.x; ls1 += u.y; ls2 += u.z; ls3 += u.w;
        lq0 += u.x*u.x; lq1 += u.y*u.y; lq2 += u.z*u.z; lq3 += u.w*u.w;
    }
    red[0][tr][tc*4+0]=ls0; red[0][tr][tc*4+1]=ls1; red[0][tr][tc*4+2]=ls2; red[0][tr][tc*4+3]=ls3;
    red[1][tr][tc*4+0]=lq0; red[1][tr][tc*4+1]=lq1; red[1][tr][tc*4+2]=lq2; red[1][tr][tc*4+3]=lq3;
    __syncthreads();
    if (t < 128){
        float a = 0.f, b = 0.f;
        #pragma unroll
        for (int q = 0; q < 8; ++q){ a += red[0][q][t]; b += red[1][q][t]; }
        atomicAdd(&sums_n[t], a);
        atomicAdd(&sums_n[256 + t], b);
    }
}

// ---------------- final: BN(elu(h)) @ W2 + b2 + x[:, :1] ----------------
__global__ __launch_bounds__(256) void k_final(const float* __restrict__ U, const float* __restrict__ sums30,
                                               const float* __restrict__ g2, const float* __restrict__ beta2,
                                               const float* __restrict__ W2, const float* __restrict__ b2,
                                               const float* __restrict__ x, float* __restrict__ out){
    __shared__ float s_s[128], s_sh[128];
    __shared__ float wred[4];
    int t = threadIdx.x;
    if (t < 128){
        float m   = sums30[t]       * (1.f / NTOT);
        float ex2 = sums30[256 + t] * (1.f / NTOT);
        float var = ex2 - m * m;
        float sc = g2[t] * rsqrtf(var + EPSBN);
        s_s[t] = sc; s_sh[t] = beta2[t] - m * sc;
    }
    __syncthreads();
    int lane = t & 63, wid = t >> 6;
    int ch = t & 127, pr = t >> 7;
    float w2 = W2[ch];
    float b2v = b2[0];
    int base = blockIdx.x * 64;
    for (int it = 0; it < 32; ++it){
        int rowa = base + it * 2;
        int row  = rowa + pr;
        float v = (U[(size_t)row * HCH + ch] * s_s[ch] + s_sh[ch]) * w2;
        #pragma unroll
        for (int off = 32; off > 0; off >>= 1) v += __shfl_down(v, off);
        if (lane == 0) wred[wid] = v;
        __syncthreads();
        if (t == 0)   out[rowa]     = wred[0] + wred[1] + b2v + x[(size_t)rowa * 3];
        if (t == 128) out[rowa + 1] = wred[2] + wred[3] + b2v + x[(size_t)(rowa + 1) * 3];
        __syncthreads();
    }
}

// ---------------- host ----------------
extern "C" void kernel_launch(void* const* d_in, const int* in_sizes, int n_in,
                              void* d_out, int out_size, void* d_ws, size_t ws_size,
                              hipStream_t stream){
    const float* x    = (const float*)d_in[0];
    const float* L    = (const float*)d_in[1];
    const float* mask = (const float*)d_in[2];
    const float* W1   = (const float*)d_in[3];
    const float* b1   = (const float*)d_in[4];
    const float* Wb   = (const float*)d_in[5];
    const float* bb   = (const float*)d_in[6];
    const float* gb   = (const float*)d_in[7];
    const float* betab= (const float*)d_in[8];
    const float* g2   = (const float*)d_in[9];
    const float* beta2= (const float*)d_in[10];
    const float* W2   = (const float*)d_in[11];
    const float* b2   = (const float*)d_in[12];
    const int*   src  = (const int*)d_in[13];
    const int*   dst  = (const int*)d_in[14];

    char* base = (char*)d_ws;
    size_t off = 0;
    auto alloc = [&](size_t bytes)->char*{
        char* r = base + off;
        off = (off + bytes + 255) & ~(size_t)255;
        return r;
    };
    float* sums  = (float*)alloc(31 * 512 * sizeof(float));       // per-layer BN sums/sumsq
    float* gsum  = (float*)alloc(30 * NGRAPH * HCH * sizeof(float));
    float* gcnt  = (float*)alloc(30 * NGRAPH * sizeof(float));
    int*   deg   = (int*)  alloc(NTOT * sizeof(int));
    size_t zero_bytes = off;                                       // everything above zeroed once
    int*   cursor= (int*)  alloc(NTOT * sizeof(int));
    int*   rowptr= (int*)  alloc((NTOT + 1) * sizeof(int));
    int*   esrc  = (int*)  alloc(EDGES * sizeof(int));
    float* ew    = (float*)alloc(EDGES * sizeof(float));
    float* H0    = (float*)alloc((size_t)NTOT * HCH * sizeof(float));
    float* U0    = (float*)alloc((size_t)NTOT * HCH * sizeof(float));
    float* U1    = (float*)alloc((size_t)NTOT * HCH * sizeof(float));
    float* AGG   = (float*)alloc((size_t)NTOT * HCH * sizeof(float));
    (void)ws_size; (void)in_sizes; (void)n_in; (void)out_size;

    hipMemsetAsync(d_ws, 0, zero_bytes, stream);
    k_hist   <<<EDGES / 256, 256, 0, stream>>>(dst, deg);
    k_scan   <<<1, 1024, 0, stream>>>(deg, rowptr, cursor);
    k_scatter<<<EDGES / 256, 256, 0, stream>>>(src, dst, L, cursor, esrc, ew);
    k_conv1  <<<NTOT / 128, 256, 0, stream>>>(x, W1, b1, H0, U0, sums);

    float* Ucur = U0; float* Unext = U1;
    for (int i = 0; i < 15; ++i){
        for (int j = 0; j < 2; ++j){
            int k = 2 * i + j;
            const float* Wk  = Wb + (size_t)k * 256 * HCH;
            const float* bk  = bb + (size_t)k * HCH;
            const float* gk  = gb + (size_t)k * 256;
            const float* bek = betab + (size_t)k * 256;
            float* sk = sums + (size_t)k * 512;
            float* sn = sums + (size_t)(k + 1) * 512;
            if ((i & 1) == 0){
                k_spmm<<<NTOT / 32, 256, 0, stream>>>(Ucur, rowptr, esrc, ew, AGG, sk);
                if (j == 0)
                    k_gemm<0,0><<<NTOT / 64, 256, 0, stream>>>(Ucur, AGG, nullptr, nullptr, sk, gk, bek,
                                                               Wk, bk, nullptr, nullptr, Unext, sn);
                else
                    k_gemm<0,1><<<NTOT / 64, 256, 0, stream>>>(Ucur, AGG, nullptr, nullptr, sk, gk, bek,
                                                               Wk, bk, H0, H0, Unext, sn);
            } else {
                float* gs = gsum + (size_t)k * NGRAPH * HCH;
                float* gc = gcnt + (size_t)k * NGRAPH;
                k_gavg<<<dim3(32, 8), 256, 0, stream>>>(Ucur, mask, gs, gc);
                if (j == 0)
                    k_gemm<1,0><<<NTOT / 64, 256, 0, stream>>>(Ucur, nullptr, gs, gc, sk, gk, bek,
                                                               Wk, bk, nullptr, nullptr, Unext, sn);
                else
                    k_gemm<1,1><<<NTOT / 64, 256, 0, stream>>>(Ucur, nullptr, gs, gc, sk, gk, bek,
                                                               Wk, bk, H0, H0, Unext, sn);
            }
            float* tmp = Ucur; Ucur = Unext; Unext = tmp;
        }
    }
    k_final<<<NTOT / 64, 256, 0, stream>>>(Ucur, sums + 30 * 512, g2, beta2, W2, b2, x, (float*)d_out);
}

// Round 2
// 2576.297 us; speedup vs baseline: 1.2410x; 1.2410x over previous
//
#include <hip/hip_runtime.h>
#include <hip/hip_bf16.h>
#include <math.h>

#define NTOT   32768
#define NPER   4096
#define NGRAPH 8
#define EDGES  262144
#define HCH    128
#define EPSBN  1e-5f

__device__ __forceinline__ float eluf(float x){ return x > 0.f ? x : expm1f(x); }

// ---------------- CSR build ----------------
__global__ __launch_bounds__(256) void k_hist(const int* __restrict__ dst, int* __restrict__ deg){
    int e = blockIdx.x * 256 + threadIdx.x;
    atomicAdd(&deg[dst[e]], 1);
}

__global__ __launch_bounds__(1024) void k_scan(const int* __restrict__ deg, int* __restrict__ rowptr,
                                               int* __restrict__ cursor){
    __shared__ int part[1024];
    int t = threadIdx.x;
    const int chunk = NTOT / 1024;            // 32
    int base = t * chunk;
    int s = 0;
    for (int j = 0; j < chunk; ++j) s += deg[base + j];
    part[t] = s; __syncthreads();
    for (int off = 1; off < 1024; off <<= 1){
        int v = (t >= off) ? part[t - off] : 0;
        __syncthreads();
        part[t] += v;
        __syncthreads();
    }
    int run = part[t] - s;                    // exclusive prefix
    for (int j = 0; j < chunk; ++j){
        rowptr[base + j] = run; cursor[base + j] = run;
        run += deg[base + j];
    }
    if (t == 1023) rowptr[NTOT] = run;
}

__global__ __launch_bounds__(256) void k_scatter(const int* __restrict__ src, const int* __restrict__ dst,
                                                 const float* __restrict__ L, int* __restrict__ cursor,
                                                 int* __restrict__ esrc, float* __restrict__ ew){
    int e = blockIdx.x * 256 + threadIdx.x;
    int d = dst[e];
    int pos = atomicAdd(&cursor[d], 1);
    esrc[pos] = src[e];
    ew[pos]   = L[e];
}

// ---------------- per-graph mask count (layer-invariant, once) ----------------
__global__ __launch_bounds__(256) void k_cnt(const float* __restrict__ mask, float* __restrict__ gcnt){
    __shared__ float red[4];
    int g = blockIdx.x, t = threadIdx.x;
    float s = 0.f;
    for (int i = t; i < NPER; i += 256) s += mask[g * NPER + i];
    #pragma unroll
    for (int off = 32; off > 0; off >>= 1) s += __shfl_down(s, off);
    if ((t & 63) == 0) red[t >> 6] = s;
    __syncthreads();
    if (t == 0) gcnt[g] = red[0] + red[1] + red[2] + red[3];
}

// ---------------- conv1: H = x@W1+b1 ; U = elu(H) ; stats -> sums[0] ----------------
__global__ __launch_bounds__(256) void k_conv1(const float* __restrict__ x, const float* __restrict__ W1,
                                               const float* __restrict__ b1, float* __restrict__ H,
                                               float* __restrict__ U, float* __restrict__ sums0){
    __shared__ float red[2][2][128];
    int t = threadIdx.x, ch = t & 127, pr = t >> 7;
    float w0 = W1[ch], w1 = W1[128 + ch], w2 = W1[256 + ch], bv = b1[ch];
    int base = blockIdx.x * 128;
    float ls = 0.f, lss = 0.f;
    for (int it = 0; it < 64; ++it){
        int row = base + 2 * it + pr;
        const float* xr = x + (size_t)row * 3;
        float h = fmaf(xr[2], w2, fmaf(xr[1], w1, fmaf(xr[0], w0, bv)));
        H[(size_t)row * HCH + ch] = h;
        float u = eluf(h);
        U[(size_t)row * HCH + ch] = u;
        ls += u; lss += u * u;
    }
    red[0][pr][ch] = ls; red[1][pr][ch] = lss;
    __syncthreads();
    if (t < 128){
        atomicAdd(&sums0[t],       red[0][0][t] + red[0][1][t]);
        atomicAdd(&sums0[256 + t], red[1][0][t] + red[1][1][t]);
    }
}

// ---------------- SpMM (CSR by dst) + BN stats for agg half ----------------
// thread = (node_local, 4 channels); 16 nodes/block (2 per thread); 2048 blocks, XCD-swizzled.
__global__ __launch_bounds__(256) void k_spmm(const float* __restrict__ U, const int* __restrict__ rowptr,
                                              const int* __restrict__ esrc, const float* __restrict__ ew,
                                              float* __restrict__ AGG, float* __restrict__ sums_k){
    __shared__ float red[2][8][128];
    const int t = threadIdx.x;
    const int nl = t >> 5;
    const int c4 = (t & 31) << 2;
    const int bid = blockIdx.x;
    const int sb = ((bid & 7) << 8) | (bid >> 3);   // graph g -> XCD g (2 MB U-segment per L2)
    const int n0 = sb * 16 + nl;
    const int n1 = n0 + 8;

    float4 acc[2];
    #pragma unroll
    for (int q = 0; q < 2; ++q){
        int node = q ? n1 : n0;
        int e0 = rowptr[node], e1 = rowptr[node + 1];
        float4 a = {0,0,0,0}, b = {0,0,0,0};
        int e = e0;
        for (; e + 2 <= e1; e += 2){
            int   s0 = esrc[e],  s1 = esrc[e + 1];
            float w0 = ew[e],    w1 = ew[e + 1];
            float4 u0 = *(const float4*)(U + (size_t)s0 * HCH + c4);
            float4 u1 = *(const float4*)(U + (size_t)s1 * HCH + c4);
            a.x = fmaf(u0.x, w0, a.x); a.y = fmaf(u0.y, w0, a.y);
            a.z = fmaf(u0.z, w0, a.z); a.w = fmaf(u0.w, w0, a.w);
            b.x = fmaf(u1.x, w1, b.x); b.y = fmaf(u1.y, w1, b.y);
            b.z = fmaf(u1.z, w1, b.z); b.w = fmaf(u1.w, w1, b.w);
        }
        if (e < e1){
            int s0 = esrc[e]; float w0 = ew[e];
            float4 u0 = *(const float4*)(U + (size_t)s0 * HCH + c4);
            a.x = fmaf(u0.x, w0, a.x); a.y = fmaf(u0.y, w0, a.y);
            a.z = fmaf(u0.z, w0, a.z); a.w = fmaf(u0.w, w0, a.w);
        }
        a.x += b.x; a.y += b.y; a.z += b.z; a.w += b.w;
        acc[q] = a;
    }
    *(float4*)(AGG + (size_t)n0 * HCH + c4) = acc[0];
    *(float4*)(AGG + (size_t)n1 * HCH + c4) = acc[1];

    red[0][nl][c4 + 0] = acc[0].x + acc[1].x;
    red[0][nl][c4 + 1] = acc[0].y + acc[1].y;
    red[0][nl][c4 + 2] = acc[0].z + acc[1].z;
    red[0][nl][c4 + 3] = acc[0].w + acc[1].w;
    red[1][nl][c4 + 0] = acc[0].x * acc[0].x + acc[1].x * acc[1].x;
    red[1][nl][c4 + 1] = acc[0].y * acc[0].y + acc[1].y * acc[1].y;
    red[1][nl][c4 + 2] = acc[0].z * acc[0].z + acc[1].z * acc[1].z;
    red[1][nl][c4 + 3] = acc[0].w * acc[0].w + acc[1].w * acc[1].w;
    __syncthreads();
    if (t < 128){
        float a = 0.f, b = 0.f;
        #pragma unroll
        for (int q = 0; q < 8; ++q){ a += red[0][q][t]; b += red[1][q][t]; }
        atomicAdd(&sums_k[128 + t], a);
        atomicAdd(&sums_k[384 + t], b);
    }
}

// ---------------- fused BN+GEMM (+bias,+residual) + ELU + next-layer stats (+next gavg sums) ----------------
template<int MODE, int RES>
__global__ __launch_bounds__(256) void k_gemm(
        const float* __restrict__ U, const float* __restrict__ AGG,
        const float* __restrict__ gsum_k, const float* __restrict__ gcnt,
        const float* __restrict__ sums_k,
        const float* __restrict__ gamma, const float* __restrict__ beta,
        const float* __restrict__ W, const float* __restrict__ bias,
        const float* __restrict__ Hres, float* __restrict__ Hout,
        float* __restrict__ Uout, float* __restrict__ sums_n,
        const float* __restrict__ mask, float* __restrict__ gsum_next)
{
    __shared__ float s_s[256], s_shift[256], s_avgn[128];
    __shared__ float zs[64][68];
    __shared__ float wsm[64][132];
    __shared__ float red[2][8][128];
    const int t = threadIdx.x;
    const int row0 = blockIdx.x * 64;

    if (t < 256){
        float m, ex2;
        if (MODE == 1 && t >= 128){
            float S1 = 0.f, S2 = 0.f;
            #pragma unroll
            for (int g = 0; g < NGRAPH; ++g){
                float a = gsum_k[g * HCH + (t - 128)] / gcnt[g];
                S1 += a; S2 += a * a;
            }
            m = S1 * (1.f / NGRAPH); ex2 = S2 * (1.f / NGRAPH);
        } else {
            m   = sums_k[t]       * (1.f / NTOT);
            ex2 = sums_k[256 + t] * (1.f / NTOT);
        }
        float var = ex2 - m * m;
        float sc = gamma[t] * rsqrtf(var + EPSBN);
        s_s[t] = sc;
        s_shift[t] = beta[t] - m * sc;
    }
    __syncthreads();
    if (MODE == 1 && t < 128){
        int g0 = row0 >> 12;
        float a = gsum_k[g0 * HCH + t] / gcnt[g0];
        s_avgn[t] = a * s_s[128 + t] + s_shift[128 + t];
        // first read of s_avgn is chunk-2 staging, >=2 barriers later
    }

    float acc[8][4];
    #pragma unroll
    for (int ri = 0; ri < 8; ++ri)
        #pragma unroll
        for (int j = 0; j < 4; ++j) acc[ri][j] = 0.f;
    const int tc = t & 31, tr = t >> 5;

    for (int chnk = 0; chnk < 4; ++chnk){
        const int cb = chnk * 64;
        #pragma unroll
        for (int i = 0; i < 4; ++i){
            int f = t + 256 * i;
            int r = f >> 4;
            int c4 = (f & 15) << 2;
            float4 v;
            if (chnk < 2){
                const float4 g4 = *(const float4*)(U + (size_t)(row0 + r) * HCH + cb + c4);
                int c = cb + c4;
                v.x = g4.x * s_s[c + 0] + s_shift[c + 0];
                v.y = g4.y * s_s[c + 1] + s_shift[c + 1];
                v.z = g4.z * s_s[c + 2] + s_shift[c + 2];
                v.w = g4.w * s_s[c + 3] + s_shift[c + 3];
            } else if (MODE == 0){
                const float4 g4 = *(const float4*)(AGG + (size_t)(row0 + r) * HCH + (cb - 128) + c4);
                int c = cb + c4;
                v.x = g4.x * s_s[c + 0] + s_shift[c + 0];
                v.y = g4.y * s_s[c + 1] + s_shift[c + 1];
                v.z = g4.z * s_s[c + 2] + s_shift[c + 2];
                v.w = g4.w * s_s[c + 3] + s_shift[c + 3];
            } else {
                int c = cb - 128 + c4;
                v.x = s_avgn[c + 0]; v.y = s_avgn[c + 1];
                v.z = s_avgn[c + 2]; v.w = s_avgn[c + 3];
            }
            *(float4*)&zs[r][c4] = v;
        }
        #pragma unroll
        for (int i = 0; i < 8; ++i){
            int f = t + 256 * i;
            int kr = f >> 5;
            int c4 = (f & 31) << 2;
            *(float4*)&wsm[kr][c4] = *(const float4*)(W + (size_t)(cb + kr) * HCH + c4);
        }
        __syncthreads();
        #pragma unroll
        for (int k = 0; k < 64; k += 4){
            float4 wv[4];
            #pragma unroll
            for (int kk = 0; kk < 4; ++kk) wv[kk] = *(const float4*)&wsm[k + kk][tc * 4];
            #pragma unroll
            for (int ri = 0; ri < 8; ++ri){
                float4 zr = *(const float4*)&zs[tr + 8 * ri][k];
                float zf[4] = {zr.x, zr.y, zr.z, zr.w};
                #pragma unroll
                for (int kk = 0; kk < 4; ++kk){
                    acc[ri][0] = fmaf(zf[kk], wv[kk].x, acc[ri][0]);
                    acc[ri][1] = fmaf(zf[kk], wv[kk].y, acc[ri][1]);
                    acc[ri][2] = fmaf(zf[kk], wv[kk].z, acc[ri][2]);
                    acc[ri][3] = fmaf(zf[kk], wv[kk].w, acc[ri][3]);
                }
            }
        }
        __syncthreads();
    }

    // epilogue: bias (+res) -> h ; u = elu(h) ; stats for next layer (+ masked per-graph sums)
    float b0 = bias[tc * 4 + 0], b1v = bias[tc * 4 + 1];
    float b2v = bias[tc * 4 + 2], b3 = bias[tc * 4 + 3];
    float ls0=0,ls1=0,ls2=0,ls3=0, lq0=0,lq1=0,lq2=0,lq3=0;
    float lm0=0,lm1=0,lm2=0,lm3=0;
    #pragma unroll
    for (int ri = 0; ri < 8; ++ri){
        int row = row0 + tr + 8 * ri;
        float4 h;
        h.x = acc[ri][0] + b0; h.y = acc[ri][1] + b1v;
        h.z = acc[ri][2] + b2v; h.w = acc[ri][3] + b3;
        if (RES){
            float4 rv = *(const float4*)(Hres + (size_t)row * HCH + tc * 4);
            h.x += rv.x; h.y += rv.y; h.z += rv.z; h.w += rv.w;
            *(float4*)(Hout + (size_t)row * HCH + tc * 4) = h;
        }
        float4 u;
        u.x = eluf(h.x); u.y = eluf(h.y); u.z = eluf(h.z); u.w = eluf(h.w);
        *(float4*)(Uout + (size_t)row * HCH + tc * 4) = u;
        ls0 += u.x; ls1 += u.y; ls2 += u.z; ls3 += u.w;
        lq0 += u.x*u.x; lq1 += u.y*u.y; lq2 += u.z*u.z; lq3 += u.w*u.w;
        if (gsum_next){
            float mk = mask[row];
            lm0 = fmaf(u.x, mk, lm0); lm1 = fmaf(u.y, mk, lm1);
            lm2 = fmaf(u.z, mk, lm2); lm3 = fmaf(u.w, mk, lm3);
        }
    }
    red[0][tr][tc*4+0]=ls0; red[0][tr][tc*4+1]=ls1; red[0][tr][tc*4+2]=ls2; red[0][tr][tc*4+3]=ls3;
    red[1][tr][tc*4+0]=lq0; red[1][tr][tc*4+1]=lq1; red[1][tr][tc*4+2]=lq2; red[1][tr][tc*4+3]=lq3;
    __syncthreads();
    if (t < 128){
        float a = 0.f, b = 0.f;
        #pragma unroll
        for (int q = 0; q < 8; ++q){ a += red[0][q][t]; b += red[1][q][t]; }
        atomicAdd(&sums_n[t], a);
        atomicAdd(&sums_n[256 + t], b);
    }
    if (gsum_next){
        __syncthreads();            // protect red reuse
        red[0][tr][tc*4+0]=lm0; red[0][tr][tc*4+1]=lm1;
        red[0][tr][tc*4+2]=lm2; red[0][tr][tc*4+3]=lm3;
        __syncthreads();
        if (t < 128){
            float a = 0.f;
            #pragma unroll
            for (int q = 0; q < 8; ++q) a += red[0][q][t];
            atomicAdd(&gsum_next[(row0 >> 12) * HCH + t], a);
        }
    }
}

// ---------------- final: BN(elu(h)) @ W2 + b2 + x[:, :1] ----------------
__global__ __launch_bounds__(256) void k_final(const float* __restrict__ U, const float* __restrict__ sums30,
                                               const float* __restrict__ g2, const float* __restrict__ beta2,
                                               const float* __restrict__ W2, const float* __restrict__ b2,
                                               const float* __restrict__ x, float* __restrict__ out){
    __shared__ float s_s[128], s_sh[128];
    __shared__ float wred[4];
    int t = threadIdx.x;
    if (t < 128){
        float m   = sums30[t]       * (1.f / NTOT);
        float ex2 = sums30[256 + t] * (1.f / NTOT);
        float var = ex2 - m * m;
        float sc = g2[t] * rsqrtf(var + EPSBN);
        s_s[t] = sc; s_sh[t] = beta2[t] - m * sc;
    }
    __syncthreads();
    int lane = t & 63, wid = t >> 6;
    int ch = t & 127, pr = t >> 7;
    float w2 = W2[ch];
    float b2v = b2[0];
    int base = blockIdx.x * 64;
    for (int it = 0; it < 32; ++it){
        int rowa = base + it * 2;
        int row  = rowa + pr;
        float v = (U[(size_t)row * HCH + ch] * s_s[ch] + s_sh[ch]) * w2;
        #pragma unroll
        for (int off = 32; off > 0; off >>= 1) v += __shfl_down(v, off);
        if (lane == 0) wred[wid] = v;
        __syncthreads();
        if (t == 0)   out[rowa]     = wred[0] + wred[1] + b2v + x[(size_t)rowa * 3];
        if (t == 128) out[rowa + 1] = wred[2] + wred[3] + b2v + x[(size_t)(rowa + 1) * 3];
        __syncthreads();
    }
}

// ---------------- host ----------------
extern "C" void kernel_launch(void* const* d_in, const int* in_sizes, int n_in,
                              void* d_out, int out_size, void* d_ws, size_t ws_size,
                              hipStream_t stream){
    const float* x    = (const float*)d_in[0];
    const float* L    = (const float*)d_in[1];
    const float* mask = (const float*)d_in[2];
    const float* W1   = (const float*)d_in[3];
    const float* b1   = (const float*)d_in[4];
    const float* Wb   = (const float*)d_in[5];
    const float* bb   = (const float*)d_in[6];
    const float* gb   = (const float*)d_in[7];
    const float* betab= (const float*)d_in[8];
    const float* g2   = (const float*)d_in[9];
    const float* beta2= (const float*)d_in[10];
    const float* W2   = (const float*)d_in[11];
    const float* b2   = (const float*)d_in[12];
    const int*   src  = (const int*)d_in[13];
    const int*   dst  = (const int*)d_in[14];

    char* base = (char*)d_ws;
    size_t off = 0;
    auto alloc = [&](size_t bytes)->char*{
        char* r = base + off;
        off = (off + bytes + 255) & ~(size_t)255;
        return r;
    };
    float* sums  = (float*)alloc(31 * 512 * sizeof(float));       // per-layer BN sums/sumsq
    float* gsum  = (float*)alloc(30 * NGRAPH * HCH * sizeof(float));
    int*   deg   = (int*)  alloc(NTOT * sizeof(int));
    size_t zero_bytes = off;                                       // zeroed once
    float* gcnt  = (float*)alloc(NGRAPH * sizeof(float));          // written by k_cnt
    int*   cursor= (int*)  alloc(NTOT * sizeof(int));
    int*   rowptr= (int*)  alloc((NTOT + 1) * sizeof(int));
    int*   esrc  = (int*)  alloc(EDGES * sizeof(int));
    float* ew    = (float*)alloc(EDGES * sizeof(float));
    float* H0    = (float*)alloc((size_t)NTOT * HCH * sizeof(float));
    float* U0    = (float*)alloc((size_t)NTOT * HCH * sizeof(float));
    float* U1    = (float*)alloc((size_t)NTOT * HCH * sizeof(float));
    float* AGG   = (float*)alloc((size_t)NTOT * HCH * sizeof(float));
    (void)ws_size; (void)in_sizes; (void)n_in; (void)out_size;

    hipMemsetAsync(d_ws, 0, zero_bytes, stream);
    k_hist   <<<EDGES / 256, 256, 0, stream>>>(dst, deg);
    k_scan   <<<1, 1024, 0, stream>>>(deg, rowptr, cursor);
    k_scatter<<<EDGES / 256, 256, 0, stream>>>(src, dst, L, cursor, esrc, ew);
    k_cnt    <<<NGRAPH, 256, 0, stream>>>(mask, gcnt);
    k_conv1  <<<NTOT / 128, 256, 0, stream>>>(x, W1, b1, H0, U0, sums);

    float* Ucur = U0; float* Unext = U1;
    for (int i = 0; i < 15; ++i){
        for (int j = 0; j < 2; ++j){
            int k = 2 * i + j;
            const float* Wk  = Wb + (size_t)k * 256 * HCH;
            const float* bk  = bb + (size_t)k * HCH;
            const float* gk  = gb + (size_t)k * 256;
            const float* bek = betab + (size_t)k * 256;
            float* sk = sums + (size_t)k * 512;
            float* sn = sums + (size_t)(k + 1) * 512;
            bool nextg = (k < 29) && ((((k + 1) / 2) & 1) == 1);
            float* gsn = nextg ? (gsum + (size_t)(k + 1) * NGRAPH * HCH) : nullptr;
            if ((i & 1) == 0){
                k_spmm<<<NTOT / 16, 256, 0, stream>>>(Ucur, rowptr, esrc, ew, AGG, sk);
                if (j == 0)
                    k_gemm<0,0><<<NTOT / 64, 256, 0, stream>>>(Ucur, AGG, nullptr, gcnt, sk, gk, bek,
                                                               Wk, bk, nullptr, nullptr, Unext, sn, mask, gsn);
                else
                    k_gemm<0,1><<<NTOT / 64, 256, 0, stream>>>(Ucur, AGG, nullptr, gcnt, sk, gk, bek,
                                                               Wk, bk, H0, H0, Unext, sn, mask, gsn);
            } else {
                float* gs = gsum + (size_t)k * NGRAPH * HCH;
                if (j == 0)
                    k_gemm<1,0><<<NTOT / 64, 256, 0, stream>>>(Ucur, nullptr, gs, gcnt, sk, gk, bek,
                                                               Wk, bk, nullptr, nullptr, Unext, sn, mask, gsn);
                else
                    k_gemm<1,1><<<NTOT / 64, 256, 0, stream>>>(Ucur, nullptr, gs, gcnt, sk, gk, bek,
                                                               Wk, bk, H0, H0, Unext, sn, mask, gsn);
            }
            float* tmp = Ucur; Ucur = Unext; Unext = tmp;
        }
    }
    k_final<<<NTOT / 64, 256, 0, stream>>>(Ucur, sums + 30 * 512, g2, beta2, W2, b2, x, (float*)d_out);
}